// Round 3
// baseline (2078.333 us; speedup 1.0000x reference)
//
#include <hip/hip_runtime.h>

// Hartley spectral conv (fp32 I/O!): B=16, Ci=Co=64, H=W=256, 64x64 modes (f=j-32).
// Verified algebra: E=Re F2, O=-Im F2 of the real-input 2D DFT at f in [-32,32)^2
// (equals (xh+xr)/2, (xh-xr)/2 of the reference via conjugate symmetry);
// kr[m] = w[flip(m)], flip(j) = (64-j)&63 per axis;
// inverse: out = (1/65536) * sum_m G_m cas(2pi(fy*y+fx*x)/256), factorized as
// x-pass (cos/sin -> H1/H2) then y-pass (casP=cos+sin, casM=cos-sin).
// R2 root cause: inputs/outputs are FLOAT32 per the reference (jnp.float32);
// previous rounds read them as bf16 -> NaNs -> relu(NaN)=0 -> all-zero output.

typedef unsigned short u16;
typedef unsigned int u32;

__device__ __forceinline__ float bf2f(u16 u) { union { u32 i; float f; } v; v.i = ((u32)u) << 16; return v.f; }
__device__ __forceinline__ u16 f2bf(float f) {
  u32 x = __float_as_uint(f);
  x += 0x7fffu + ((x >> 16) & 1u);   // round-to-nearest-even
  return (u16)(x >> 16);
}

// ---------------- K0: trig tables ----------------
// cosT[t*64+k] = cos(2*pi*(k-32)*t/256)   [t-major, for forward]
// cosTT/sinTT/casPT/casMT are [k][t]      [k-major, for inverse]
__global__ __launch_bounds__(256) void k0_trig(float* __restrict__ cosT, float* __restrict__ sinT,
                                               float* __restrict__ cosTT, float* __restrict__ sinTT,
                                               float* __restrict__ casPT, float* __restrict__ casMT) {
  int idx = blockIdx.x * 256 + threadIdx.x;  // 16384
  int t = idx >> 6, k = idx & 63;
  int m = (((k - 32) * t) % 256 + 256) & 255;      // exact periodic reduction
  float ang = (float)m * 0.0245436926061702596f;   // 2*pi/256
  float s, c;
  sincosf(ang, &s, &c);
  cosT[t * 64 + k] = c;   sinT[t * 64 + k] = s;
  cosTT[k * 256 + t] = c; sinTT[k * 256 + t] = s;
  casPT[k * 256 + t] = c + s; casMT[k * 256 + t] = c - s;
}

// ---------------- kFwd: fused 2D forward partial DFT, one block per image ----------------
// Phase 1: A[y][j] = sum_x X[y][x] cos(x,j), B = sum sin  -> LDS (bf16)
// Phase 2: E[fy][fx] = sum_y cos(y,fy) A[y][fx] - sin(y,fy) B[y][fx]
//          O[fy][fx] = sum_y sin(y,fy) A[y][fx] + cos(y,fy) B[y][fx]
__global__ __launch_bounds__(256) void kFwd(const float* __restrict__ x,
    const float* __restrict__ cosT, const float* __restrict__ sinT,
    u16* __restrict__ E, u16* __restrict__ O) {
  __shared__ u16 Als[16384];   // [y][j] 256x64, 32 KiB
  __shared__ u16 Bls[16384];
  const int t = threadIdx.x;
  const int img = blockIdx.x;                  // b*64 + ci
  const long xbase = (long)img * 65536;
  { // phase 1
    const int j = t & 63, yg = t >> 6;
    for (int yt = 0; yt < 8; ++yt) {
      const int y0 = yg * 64 + yt * 8;
      float aC[8], aS[8];
#pragma unroll
      for (int r = 0; r < 8; ++r) { aC[r] = 0.f; aS[r] = 0.f; }
      for (int xx = 0; xx < 256; ++xx) {
        float c = cosT[xx * 64 + j];
        float s = sinT[xx * 64 + j];
#pragma unroll
        for (int r = 0; r < 8; ++r) {
          float xv = x[xbase + (y0 + r) * 256 + xx];   // wave-uniform addr -> broadcast
          aC[r] = fmaf(xv, c, aC[r]);
          aS[r] = fmaf(xv, s, aS[r]);
        }
      }
#pragma unroll
      for (int r = 0; r < 8; ++r) {
        Als[(y0 + r) * 64 + j] = f2bf(aC[r]);
        Bls[(y0 + r) * 64 + j] = f2bf(aS[r]);
      }
    }
  }
  __syncthreads();
  { // phase 2
    const int fx = t & 63, fyg = t >> 6;
    float aE[16], aO[16];
#pragma unroll
    for (int r = 0; r < 16; ++r) { aE[r] = 0.f; aO[r] = 0.f; }
    for (int y = 0; y < 256; ++y) {
      float a = bf2f(Als[y * 64 + fx]);
      float b = bf2f(Bls[y * 64 + fx]);
#pragma unroll
      for (int r = 0; r < 16; ++r) {
        float c = cosT[y * 64 + fyg * 16 + r];   // wave-uniform -> s_load
        float s = sinT[y * 64 + fyg * 16 + r];
        aE[r] = fmaf(c, a, fmaf(-s, b, aE[r]));
        aO[r] = fmaf(s, a, fmaf(c, b, aO[r]));
      }
    }
#pragma unroll
    for (int r = 0; r < 16; ++r) {
      int fy = fyg * 16 + r;
      E[(long)img * 4096 + fy * 64 + fx] = f2bf(aE[r]);
      O[(long)img * 4096 + fy * 64 + fx] = f2bf(aO[r]);
    }
  }
}

// ---------------- u16 transpose: in[M][N] -> out[N][M] (z selects pair) ----------------
__global__ __launch_bounds__(256) void kt_u16(const u16* __restrict__ in0, u16* __restrict__ out0,
                                              const u16* __restrict__ in1, u16* __restrict__ out1,
                                              int M, int N) {
  __shared__ u16 tile[32][36];
  const u16* in = blockIdx.z ? in1 : in0;
  u16* out = blockIdx.z ? out1 : out0;
  int tx = threadIdx.x & 31, ty = threadIdx.x >> 5;
  long c0 = (long)blockIdx.x * 32, r0 = (long)blockIdx.y * 32;
#pragma unroll
  for (int i = 0; i < 4; ++i) {
    int r = ty + i * 8;
    tile[r][tx] = in[(r0 + r) * N + c0 + tx];
  }
  __syncthreads();
#pragma unroll
  for (int i = 0; i < 4; ++i) {
    int r = ty + i * 8;
    out[(c0 + r) * M + r0 + tx] = tile[tx][r];
  }
}

// ---------------- k5: per-mode channel mix, G[b][o] = sum_i E*w + O*kr ----------------
// w is fp32 [i][o][jy][jx]; element (i*64+o)*4096 + mode. kr via flipped mode fm.
__global__ __launch_bounds__(256) void k5_mix(const u16* __restrict__ Et, const u16* __restrict__ Ot,
    const float* __restrict__ w, u16* __restrict__ Gt) {
  __shared__ float Ews[1024], Ows[1024];   // [img = b*64+i]
  __shared__ float Ws[4096], Ks[4096];     // [i*64+o]
  const int t = threadIdx.x;
  const int mode = blockIdx.x;
  const int jy = mode >> 6, jx = mode & 63;
  const int fm = (((64 - jy) & 63) << 6) | ((64 - jx) & 63);
  ushort4 ve = ((const ushort4*)Et)[(long)mode * 256 + t];
  ushort4 vo = ((const ushort4*)Ot)[(long)mode * 256 + t];
  Ews[t * 4 + 0] = bf2f(ve.x); Ews[t * 4 + 1] = bf2f(ve.y);
  Ews[t * 4 + 2] = bf2f(ve.z); Ews[t * 4 + 3] = bf2f(ve.w);
  Ows[t * 4 + 0] = bf2f(vo.x); Ows[t * 4 + 1] = bf2f(vo.y);
  Ows[t * 4 + 2] = bf2f(vo.z); Ows[t * 4 + 3] = bf2f(vo.w);
#pragma unroll
  for (int it = 0; it < 16; ++it) {
    int e = it * 256 + t;
    Ws[e] = w[(long)e * 4096 + mode];
    Ks[e] = w[(long)e * 4096 + fm];
  }
  __syncthreads();
  const int o = t & 63, bg = t >> 6;
  float acc[4] = {0.f, 0.f, 0.f, 0.f};
  for (int i = 0; i < 64; ++i) {
    float wv = Ws[i * 64 + o];
    float kv = Ks[i * 64 + o];
#pragma unroll
    for (int j = 0; j < 4; ++j) {
      int b = bg * 4 + j;
      acc[j] = fmaf(Ews[b * 64 + i], wv, acc[j]);
      acc[j] = fmaf(Ows[b * 64 + i], kv, acc[j]);
    }
  }
#pragma unroll
  for (int j = 0; j < 4; ++j)
    Gt[(long)mode * 1024 + (bg * 4 + j) * 64 + o] = f2bf(acc[j]);
}

// ---------------- kInv: fused 2D inverse, one block per output image (bo) ----------------
// Phase 1: H1[jy][x] = sum_jx G[jy][jx] cos(jx,x); H2 = sum sin -> LDS bf16
// Phase 2: out[y][x] = relu( (sum_jy casP(jy,y) H1 + casM(jy,y) H2)/65536 + bias[o] )
__global__ __launch_bounds__(256) void kInv(const u16* __restrict__ G,
    const float* __restrict__ cosTT, const float* __restrict__ sinTT,
    const float* __restrict__ casPT, const float* __restrict__ casMT,
    const float* __restrict__ bias, float* __restrict__ out) {
  __shared__ u16 H1s[16384];   // [jy][x] 64x256
  __shared__ u16 H2s[16384];
  const int t = threadIdx.x;   // x
  const int bo = blockIdx.x;   // b*64 + o
  const long gbase = (long)bo * 4096;
  for (int jyt = 0; jyt < 8; ++jyt) {
    const int jy0 = jyt * 8;
    float a1[8], a2[8];
#pragma unroll
    for (int r = 0; r < 8; ++r) { a1[r] = 0.f; a2[r] = 0.f; }
    for (int jx = 0; jx < 64; ++jx) {
      float c = cosTT[jx * 256 + t];
      float s = sinTT[jx * 256 + t];
#pragma unroll
      for (int r = 0; r < 8; ++r) {
        float g = bf2f(G[gbase + (jy0 + r) * 64 + jx]);   // wave-uniform -> scalarizable
        a1[r] = fmaf(g, c, a1[r]);
        a2[r] = fmaf(g, s, a2[r]);
      }
    }
#pragma unroll
    for (int r = 0; r < 8; ++r) {
      H1s[(jy0 + r) * 256 + t] = f2bf(a1[r]);
      H2s[(jy0 + r) * 256 + t] = f2bf(a2[r]);
    }
  }
  __syncthreads();
  const float bv = bias[bo & 63];
  const float inv = 1.0f / 65536.0f;
  for (int yt = 0; yt < 32; ++yt) {
    const int y0 = yt * 8;
    float acc[8];
#pragma unroll
    for (int r = 0; r < 8; ++r) acc[r] = 0.f;
    for (int fy = 0; fy < 64; ++fy) {
      float h1 = bf2f(H1s[fy * 256 + t]);
      float h2 = bf2f(H2s[fy * 256 + t]);
#pragma unroll
      for (int r = 0; r < 8; ++r) {
        float p = casPT[fy * 256 + y0 + r];   // wave-uniform -> s_load
        float m = casMT[fy * 256 + y0 + r];
        acc[r] = fmaf(p, h1, fmaf(m, h2, acc[r]));
      }
    }
#pragma unroll
    for (int r = 0; r < 8; ++r) {
      float v = fmaf(acc[r], inv, bv);
      out[(long)bo * 65536 + (y0 + r) * 256 + t] = fmaxf(v, 0.f);
    }
  }
}

extern "C" void kernel_launch(void* const* d_in, const int* in_sizes, int n_in,
                              void* d_out, int out_size, void* d_ws, size_t ws_size,
                              hipStream_t stream) {
  const float* x    = (const float*)d_in[0];   // [16][64][256][256] fp32
  const float* w    = (const float*)d_in[1];   // [64][64][64][64]   fp32
  const float* bias = (const float*)d_in[2];   // [64]               fp32
  float* out = (float*)d_out;                  // [16][64][256][256] fp32
  char* ws = (char*)d_ws;

  // trig tables: 6 x 64 KiB
  float* cosT  = (float*)(ws + 0);
  float* sinT  = (float*)(ws + 65536);
  float* cosTT = (float*)(ws + 131072);
  float* sinTT = (float*)(ws + 196608);
  float* casPT = (float*)(ws + 262144);
  float* casMT = (float*)(ws + 327680);
  // E/O [img][mode] bf16, 8 MiB each; Gt reuses E's slot, G reuses O's slot
  u16* E  = (u16*)(ws + 393216);
  u16* O  = (u16*)(ws + 8781824);
  u16* Et = (u16*)(ws + 17170432);
  u16* Ot = (u16*)(ws + 25559040);
  u16* Gt = (u16*)(ws + 393216);     // over dead E
  u16* G  = (u16*)(ws + 8781824);    // over dead O
  // total workspace: 33,947,648 bytes (~32.4 MB)

  k0_trig<<<64,   256, 0, stream>>>(cosT, sinT, cosTT, sinTT, casPT, casMT);
  kFwd   <<<1024, 256, 0, stream>>>(x, cosT, sinT, E, O);
  kt_u16 <<<dim3(128, 32, 2), 256, 0, stream>>>(E, Et, O, Ot, 1024, 4096);
  k5_mix <<<4096, 256, 0, stream>>>(Et, Ot, w, Gt);
  kt_u16 <<<dim3(32, 128, 1), 256, 0, stream>>>(Gt, G, Gt, G, 4096, 1024);
  kInv   <<<1024, 256, 0, stream>>>(G, cosTT, sinTT, casPT, casMT, bias, out);
}